// Round 3
// baseline (222.035 us; speedup 1.0000x reference)
//
#include <hip/hip_runtime.h>
#include <hip/hip_bf16.h>
#include <hip/hip_fp16.h>

#define S_LEN  2048
#define BATCH  2
#define DMODEL 1024
#define NHEADS 16
#define HD     64
#define MROWS  4096   // S*B

using f16 = _Float16;
typedef __attribute__((ext_vector_type(8))) _Float16 f16x8;
typedef __attribute__((ext_vector_type(4))) float    f32x4;

// ---------------- RoPE cos/sin table: [S][16] ----------------
__global__ __launch_bounds__(256) void rope_table(float* __restrict__ rc, float* __restrict__ rs)
{
    int idx = blockIdx.x * 256 + threadIdx.x;   // S*16 threads
    int s = idx >> 4, i = idx & 15;
    float inv = powf(10000.0f, -(float)(2 * i) / 32.0f);
    float ang = (float)s * inv;
    rc[idx] = cosf(ang);
    rs[idx] = sinf(ang);
}

// ---------------- batched projection GEMM + bias + RoPE + head-split ----------------
// X, W are fp32 in global; converted to f16 during LDS staging.
// out[r][n] = sum_k X[r][k] * W[n][k] + b[n]; r=(s,b); RoPE on q,k; q scaled 1/8
// q,k stored (B,H,S,hd); v stored transposed (B,H,hd,S)
__global__ __launch_bounds__(256) void proj_gemm(
    const float* __restrict__ Xq, const float* __restrict__ Xk, const float* __restrict__ Xv,
    const float* __restrict__ Wq, const float* __restrict__ Wk, const float* __restrict__ Wv,
    const float* __restrict__ bq, const float* __restrict__ bk, const float* __restrict__ bv,
    f16* __restrict__ qo, f16* __restrict__ ko, f16* __restrict__ vo,
    const float* __restrict__ rc, const float* __restrict__ rs)
{
    const int mode = blockIdx.z;            // 0=q 1=k 2=v
    const float* X    = (mode == 0) ? Xq : (mode == 1) ? Xk : Xv;
    const float* W    = (mode == 0) ? Wq : (mode == 1) ? Wk : Wv;
    const float* bias = (mode == 0) ? bq : (mode == 1) ? bk : bv;

    __shared__ f16 Al[128 * 40];   // stride 40 elems (80B): 2-way bank aliasing only (free)
    __shared__ f16 Bl[128 * 40];

    const int t = threadIdx.x;
    const int lane = t & 63, wid = t >> 6;
    const int wr = wid >> 1, wc = wid & 1;
    const int m0 = blockIdx.x * 128, n0 = blockIdx.y * 128;

    f32x4 acc[4][4];
    #pragma unroll
    for (int m = 0; m < 4; m++)
        #pragma unroll
        for (int n = 0; n < 4; n++)
            acc[m][n] = f32x4{0.f, 0.f, 0.f, 0.f};

    for (int k0 = 0; k0 < DMODEL; k0 += 32) {
        __syncthreads();
        #pragma unroll
        for (int i = 0; i < 2; i++) {
            int e = (i * 256 + t) * 8;       // elem index in 128x32 tile
            int r = e >> 5, c = e & 31;
            {
                const float* src = &X[(size_t)(m0 + r) * DMODEL + k0 + c];
                float4 v0 = *reinterpret_cast<const float4*>(src);
                float4 v1 = *reinterpret_cast<const float4*>(src + 4);
                f16x8 h = { (f16)v0.x, (f16)v0.y, (f16)v0.z, (f16)v0.w,
                            (f16)v1.x, (f16)v1.y, (f16)v1.z, (f16)v1.w };
                *reinterpret_cast<f16x8*>(&Al[r * 40 + c]) = h;
            }
            {
                const float* src = &W[(size_t)(n0 + r) * DMODEL + k0 + c];
                float4 v0 = *reinterpret_cast<const float4*>(src);
                float4 v1 = *reinterpret_cast<const float4*>(src + 4);
                f16x8 h = { (f16)v0.x, (f16)v0.y, (f16)v0.z, (f16)v0.w,
                            (f16)v1.x, (f16)v1.y, (f16)v1.z, (f16)v1.w };
                *reinterpret_cast<f16x8*>(&Bl[r * 40 + c]) = h;
            }
        }
        __syncthreads();
        f16x8 a[4], b[4];
        #pragma unroll
        for (int m = 0; m < 4; m++)
            a[m] = *reinterpret_cast<const f16x8*>(&Al[(wr * 64 + m * 16 + (lane & 15)) * 40 + (lane >> 4) * 8]);
        #pragma unroll
        for (int n = 0; n < 4; n++)
            b[n] = *reinterpret_cast<const f16x8*>(&Bl[(wc * 64 + n * 16 + (lane & 15)) * 40 + (lane >> 4) * 8]);
        #pragma unroll
        for (int m = 0; m < 4; m++)
            #pragma unroll
            for (int n = 0; n < 4; n++)
                acc[m][n] = __builtin_amdgcn_mfma_f32_16x16x32_f16(a[m], b[n], acc[m][n], 0, 0, 0);
    }

    const int rowb = m0 + wr * 64, colb = n0 + wc * 64;
    #pragma unroll
    for (int n = 0; n < 4; n++) {
        int cN = colb + n * 16 + (lane & 15);
        float bvv = bias[cN];
        int h = cN >> 6, d = cN & 63;
        #pragma unroll
        for (int m = 0; m < 4; m++) {
            #pragma unroll
            for (int rg = 0; rg < 4; rg++) {
                int r = rowb + m * 16 + (lane >> 4) * 4 + rg;
                int s = r >> 1, bi = r & 1;                 // row = s*B + b, B=2
                float val = acc[m][n][rg] + bvv;
                if (mode < 2) {
                    float pv = __shfl_xor(val, 1);          // partner col cN^1 == lane^1
                    if (d < 32) {
                        int fi = d >> 1;
                        float cc = rc[s * 16 + fi], ss = rs[s * 16 + fi];
                        val = ((d & 1) == 0) ? val * cc - pv * ss : val * cc + pv * ss;
                    }
                    if (mode == 0) val *= 0.125f;           // fold 1/sqrt(hd) into q
                    ((mode == 0) ? qo : ko)[(((size_t)bi * NHEADS + h) * S_LEN + s) * HD + d] = (f16)val;
                } else {
                    vo[(((size_t)bi * NHEADS + h) * HD + d) * S_LEN + s] = (f16)val;
                }
            }
        }
    }
}

// ---------------- flash attention ----------------
// grid (S/64, B*H); 4 waves x 16 q-rows. K LDS [64][72], V^T LDS [64][72], per-wave P [16][72]
__global__ __launch_bounds__(256) void attn_fwd(
    const f16* __restrict__ qb, const f16* __restrict__ kb,
    const f16* __restrict__ vt, f16* __restrict__ ctx)
{
    __shared__ f16 Kl[64 * 72];
    __shared__ f16 Vl[64 * 72];
    __shared__ f16 Pl[4 * 16 * 72];

    const int t = threadIdx.x, lane = t & 63, wid = t >> 6;
    const int bh = blockIdx.y;
    const int q0 = blockIdx.x * 64 + wid * 16;

    const f16* qptr = qb + ((size_t)bh * S_LEN + q0) * HD;
    f16x8 qf0 = *reinterpret_cast<const f16x8*>(&qptr[(lane & 15) * HD + (lane >> 4) * 8]);
    f16x8 qf1 = *reinterpret_cast<const f16x8*>(&qptr[(lane & 15) * HD + (lane >> 4) * 8 + 32]);

    f32x4 ctxa[4];
    #pragma unroll
    for (int i = 0; i < 4; i++) ctxa[i] = f32x4{0.f, 0.f, 0.f, 0.f};
    float mrun[4], lrun[4];
    #pragma unroll
    for (int i = 0; i < 4; i++) { mrun[i] = -3.0e38f; lrun[i] = 0.f; }

    // staging map: 256 threads cover 64x64 f16 tile with TWO 8-elem (16B) stores each
    const int r_st = t >> 2, c_st = (t & 3) * 16;
    const f16* kg = kb + (size_t)bh * S_LEN * HD;
    const f16* vg = vt + (size_t)bh * HD * S_LEN;

    for (int kt = 0; kt < S_LEN / 64; kt++) {
        __syncthreads();
        {
            const f16* ks = &kg[(size_t)(kt * 64 + r_st) * HD + c_st];
            *reinterpret_cast<uint4*>(&Kl[r_st * 72 + c_st])     = *reinterpret_cast<const uint4*>(ks);
            *reinterpret_cast<uint4*>(&Kl[r_st * 72 + c_st + 8]) = *reinterpret_cast<const uint4*>(ks + 8);
            const f16* vs = &vg[(size_t)r_st * S_LEN + kt * 64 + c_st];
            *reinterpret_cast<uint4*>(&Vl[r_st * 72 + c_st])     = *reinterpret_cast<const uint4*>(vs);
            *reinterpret_cast<uint4*>(&Vl[r_st * 72 + c_st + 8]) = *reinterpret_cast<const uint4*>(vs + 8);
        }
        __syncthreads();

        // scores: 16 q-rows x 64 k-cols (4 frags of 16)
        f32x4 sc[4];
        #pragma unroll
        for (int f = 0; f < 4; f++) {
            f16x8 kf0 = *reinterpret_cast<const f16x8*>(&Kl[(f * 16 + (lane & 15)) * 72 + (lane >> 4) * 8]);
            f16x8 kf1 = *reinterpret_cast<const f16x8*>(&Kl[(f * 16 + (lane & 15)) * 72 + (lane >> 4) * 8 + 32]);
            f32x4 z = {0.f, 0.f, 0.f, 0.f};
            z = __builtin_amdgcn_mfma_f32_16x16x32_f16(qf0, kf0, z, 0, 0, 0);
            sc[f] = __builtin_amdgcn_mfma_f32_16x16x32_f16(qf1, kf1, z, 0, 0, 0);
        }

        // online softmax; C layout: row=(lane>>4)*4+rg, col=lane&15 -> row reduce = 16-lane group
        float mnew[4], tsum[4];
        #pragma unroll
        for (int rg = 0; rg < 4; rg++) {
            float mt = fmaxf(fmaxf(sc[0][rg], sc[1][rg]), fmaxf(sc[2][rg], sc[3][rg]));
            mt = fmaxf(mt, __shfl_xor(mt, 1));
            mt = fmaxf(mt, __shfl_xor(mt, 2));
            mt = fmaxf(mt, __shfl_xor(mt, 4));
            mt = fmaxf(mt, __shfl_xor(mt, 8));
            mnew[rg] = fmaxf(mrun[rg], mt);
            tsum[rg] = 0.f;
        }
        #pragma unroll
        for (int f = 0; f < 4; f++)
            #pragma unroll
            for (int rg = 0; rg < 4; rg++) {
                float p = __expf(sc[f][rg] - mnew[rg]);
                sc[f][rg] = p;
                tsum[rg] += p;
            }
        #pragma unroll
        for (int rg = 0; rg < 4; rg++) {
            float ts = tsum[rg];
            ts += __shfl_xor(ts, 1); ts += __shfl_xor(ts, 2);
            ts += __shfl_xor(ts, 4); ts += __shfl_xor(ts, 8);
            float scale = __expf(mrun[rg] - mnew[rg]);
            lrun[rg] = lrun[rg] * scale + ts;
            mrun[rg] = mnew[rg];
            #pragma unroll
            for (int n = 0; n < 4; n++) ctxa[n][rg] *= scale;
        }

        // P -> per-wave LDS (re-fragment for PV A-operand)
        #pragma unroll
        for (int f = 0; f < 4; f++)
            #pragma unroll
            for (int rg = 0; rg < 4; rg++)
                Pl[wid * 1152 + ((lane >> 4) * 4 + rg) * 72 + f * 16 + (lane & 15)] = (f16)sc[f][rg];
        __syncthreads();   // P visible; also quiesce before next-iter restage

        // PV: ctx[16 q][64 hd] += P[16][64] @ V[64][64]
        #pragma unroll
        for (int c = 0; c < 2; c++) {
            f16x8 pf = *reinterpret_cast<const f16x8*>(&Pl[wid * 1152 + (lane & 15) * 72 + (lane >> 4) * 8 + c * 32]);
            #pragma unroll
            for (int n = 0; n < 4; n++) {
                f16x8 vf = *reinterpret_cast<const f16x8*>(&Vl[(n * 16 + (lane & 15)) * 72 + (lane >> 4) * 8 + c * 32]);
                ctxa[n] = __builtin_amdgcn_mfma_f32_16x16x32_f16(pf, vf, ctxa[n], 0, 0, 0);
            }
        }
    }

    const int bi = bh >> 4, h = bh & 15;
    #pragma unroll
    for (int n = 0; n < 4; n++)
        #pragma unroll
        for (int rg = 0; rg < 4; rg++) {
            int s = q0 + (lane >> 4) * 4 + rg;
            float v = ctxa[n][rg] / lrun[rg];
            ctx[((size_t)s * BATCH + bi) * DMODEL + h * HD + n * 16 + (lane & 15)] = (f16)v;
        }
}

// ---------------- output projection: f16 X (ws), fp32 W (global), fp32 out ----------------
__global__ __launch_bounds__(256) void out_gemm(
    const f16* __restrict__ X, const float* __restrict__ W,
    const float* __restrict__ bias, float* __restrict__ out)
{
    __shared__ f16 Al[128 * 40];
    __shared__ f16 Bl[128 * 40];

    const int t = threadIdx.x;
    const int lane = t & 63, wid = t >> 6;
    const int wr = wid >> 1, wc = wid & 1;
    const int m0 = blockIdx.x * 128, n0 = blockIdx.y * 128;

    f32x4 acc[4][4];
    #pragma unroll
    for (int m = 0; m < 4; m++)
        #pragma unroll
        for (int n = 0; n < 4; n++)
            acc[m][n] = f32x4{0.f, 0.f, 0.f, 0.f};

    for (int k0 = 0; k0 < DMODEL; k0 += 32) {
        __syncthreads();
        #pragma unroll
        for (int i = 0; i < 2; i++) {
            int e = (i * 256 + t) * 8;
            int r = e >> 5, c = e & 31;
            *reinterpret_cast<uint4*>(&Al[r * 40 + c]) =
                *reinterpret_cast<const uint4*>(&X[(size_t)(m0 + r) * DMODEL + k0 + c]);
            {
                const float* src = &W[(size_t)(n0 + r) * DMODEL + k0 + c];
                float4 v0 = *reinterpret_cast<const float4*>(src);
                float4 v1 = *reinterpret_cast<const float4*>(src + 4);
                f16x8 h = { (f16)v0.x, (f16)v0.y, (f16)v0.z, (f16)v0.w,
                            (f16)v1.x, (f16)v1.y, (f16)v1.z, (f16)v1.w };
                *reinterpret_cast<f16x8*>(&Bl[r * 40 + c]) = h;
            }
        }
        __syncthreads();
        f16x8 a[4], b[4];
        #pragma unroll
        for (int m = 0; m < 4; m++)
            a[m] = *reinterpret_cast<const f16x8*>(&Al[(wr * 64 + m * 16 + (lane & 15)) * 40 + (lane >> 4) * 8]);
        #pragma unroll
        for (int n = 0; n < 4; n++)
            b[n] = *reinterpret_cast<const f16x8*>(&Bl[(wc * 64 + n * 16 + (lane & 15)) * 40 + (lane >> 4) * 8]);
        #pragma unroll
        for (int m = 0; m < 4; m++)
            #pragma unroll
            for (int n = 0; n < 4; n++)
                acc[m][n] = __builtin_amdgcn_mfma_f32_16x16x32_f16(a[m], b[n], acc[m][n], 0, 0, 0);
    }

    const int rowb = m0 + wr * 64, colb = n0 + wc * 64;
    #pragma unroll
    for (int n = 0; n < 4; n++) {
        int cN = colb + n * 16 + (lane & 15);
        float bvv = bias[cN];
        #pragma unroll
        for (int m = 0; m < 4; m++) {
            #pragma unroll
            for (int rg = 0; rg < 4; rg++) {
                int r = rowb + m * 16 + (lane >> 4) * 4 + rg;
                out[(size_t)r * DMODEL + cN] = acc[m][n][rg] + bvv;
            }
        }
    }
}

// ---------------- launch ----------------
extern "C" void kernel_launch(void* const* d_in, const int* in_sizes, int n_in,
                              void* d_out, int out_size, void* d_ws, size_t ws_size,
                              hipStream_t stream)
{
    const float* Q  = (const float*)d_in[0];
    const float* K  = (const float*)d_in[1];
    const float* V  = (const float*)d_in[2];
    const float* Wq = (const float*)d_in[3];
    const float* bq = (const float*)d_in[4];
    const float* Wk = (const float*)d_in[5];
    const float* bk = (const float*)d_in[6];
    const float* Wv = (const float*)d_in[7];
    const float* bv = (const float*)d_in[8];
    const float* Wo = (const float*)d_in[9];
    const float* bo = (const float*)d_in[10];
    float* out = (float*)d_out;

    // workspace layout (total 32.25 MiB):
    //   [0,128K)    rc    [128K,256K) rs
    //   [256K, +8M) qbuf  (B,H,S,hd) f16
    //   [+8M,+16M)  kbuf  (B,H,S,hd) f16
    //   [+16M,+24M) vtb   (B,H,hd,S) f16
    //   [+24M,+32M) ctxb  (S*B, D)   f16
    char* w = (char*)d_ws;
    const size_t szT = (size_t)S_LEN * 16 * sizeof(float);     // 128 KiB
    const size_t szQ = (size_t)MROWS * DMODEL * sizeof(f16);   // 8 MiB
    float* rc  = (float*)(w);
    float* rs  = (float*)(w + szT);
    f16* qbuf = (f16*)(w + 2 * szT);
    f16* kbuf = (f16*)(w + 2 * szT + szQ);
    f16* vtb  = (f16*)(w + 2 * szT + 2 * szQ);
    f16* ctxb = (f16*)(w + 2 * szT + 3 * szQ);

    rope_table<<<(S_LEN * 16) / 256, 256, 0, stream>>>(rc, rs);

    proj_gemm<<<dim3(MROWS / 128, DMODEL / 128, 3), 256, 0, stream>>>(
        Q, K, V, Wq, Wk, Wv, bq, bk, bv, qbuf, kbuf, vtb, rc, rs);

    attn_fwd<<<dim3(S_LEN / 64, BATCH * NHEADS), 256, 0, stream>>>(qbuf, kbuf, vtb, ctxb);

    out_gemm<<<dim3(MROWS / 128, DMODEL / 128), 256, 0, stream>>>(ctxb, Wo, bo, out);
}

// Round 6
// 183.377 us; speedup vs baseline: 1.2108x; 1.2108x over previous
//
#include <hip/hip_runtime.h>
#include <hip/hip_bf16.h>
#include <hip/hip_fp16.h>

#define S_LEN  2048
#define BATCH  2
#define DMODEL 1024
#define NHEADS 16
#define HD     64
#define MROWS  4096   // S*B

using f16 = _Float16;
typedef __attribute__((ext_vector_type(8))) _Float16 f16x8;
typedef __attribute__((ext_vector_type(4))) _Float16 f16x4;
typedef __attribute__((ext_vector_type(4))) float    f32x4;

// ---------------- RoPE cos/sin table: [S][16] ----------------
__global__ __launch_bounds__(256) void rope_table(float* __restrict__ rc, float* __restrict__ rs)
{
    int idx = blockIdx.x * 256 + threadIdx.x;   // S*16 threads
    int s = idx >> 4, i = idx & 15;
    float inv = powf(10000.0f, -(float)(2 * i) / 32.0f);
    float ang = (float)s * inv;
    rc[idx] = cosf(ang);
    rs[idx] = sinf(ang);
}

// ---------------- batched projection GEMM + bias + RoPE + head-split ----------------
// X, W are fp32 in global; converted to f16 during LDS staging.
// out[r][n] = sum_k X[r][k] * W[n][k] + b[n]; r=(s,b); RoPE on q,k
// q scaled by (1/8)*log2(e) so attention scores live in the base-2 domain.
// q,k stored (B,H,S,hd); v stored transposed (B,H,hd,S)
__global__ __launch_bounds__(256) void proj_gemm(
    const float* __restrict__ Xq, const float* __restrict__ Xk, const float* __restrict__ Xv,
    const float* __restrict__ Wq, const float* __restrict__ Wk, const float* __restrict__ Wv,
    const float* __restrict__ bq, const float* __restrict__ bk, const float* __restrict__ bv,
    f16* __restrict__ qo, f16* __restrict__ ko, f16* __restrict__ vo,
    const float* __restrict__ rc, const float* __restrict__ rs)
{
    const int mode = blockIdx.z;            // 0=q 1=k 2=v
    const float* X    = (mode == 0) ? Xq : (mode == 1) ? Xk : Xv;
    const float* W    = (mode == 0) ? Wq : (mode == 1) ? Wk : Wv;
    const float* bias = (mode == 0) ? bq : (mode == 1) ? bk : bv;

    __shared__ f16 Al[128 * 40];   // stride 40 elems (80B): 2-way bank aliasing only (free)
    __shared__ f16 Bl[128 * 40];

    const int t = threadIdx.x;
    const int lane = t & 63, wid = t >> 6;
    const int wr = wid >> 1, wc = wid & 1;
    const int m0 = blockIdx.x * 128, n0 = blockIdx.y * 128;

    f32x4 acc[4][4];
    #pragma unroll
    for (int m = 0; m < 4; m++)
        #pragma unroll
        for (int n = 0; n < 4; n++)
            acc[m][n] = f32x4{0.f, 0.f, 0.f, 0.f};

    for (int k0 = 0; k0 < DMODEL; k0 += 32) {
        __syncthreads();
        #pragma unroll
        for (int i = 0; i < 2; i++) {
            int e = (i * 256 + t) * 8;       // elem index in 128x32 tile
            int r = e >> 5, c = e & 31;
            {
                const float* src = &X[(size_t)(m0 + r) * DMODEL + k0 + c];
                float4 v0 = *reinterpret_cast<const float4*>(src);
                float4 v1 = *reinterpret_cast<const float4*>(src + 4);
                f16x8 h = { (f16)v0.x, (f16)v0.y, (f16)v0.z, (f16)v0.w,
                            (f16)v1.x, (f16)v1.y, (f16)v1.z, (f16)v1.w };
                *reinterpret_cast<f16x8*>(&Al[r * 40 + c]) = h;
            }
            {
                const float* src = &W[(size_t)(n0 + r) * DMODEL + k0 + c];
                float4 v0 = *reinterpret_cast<const float4*>(src);
                float4 v1 = *reinterpret_cast<const float4*>(src + 4);
                f16x8 h = { (f16)v0.x, (f16)v0.y, (f16)v0.z, (f16)v0.w,
                            (f16)v1.x, (f16)v1.y, (f16)v1.z, (f16)v1.w };
                *reinterpret_cast<f16x8*>(&Bl[r * 40 + c]) = h;
            }
        }
        __syncthreads();
        f16x8 a[4], b[4];
        #pragma unroll
        for (int m = 0; m < 4; m++)
            a[m] = *reinterpret_cast<const f16x8*>(&Al[(wr * 64 + m * 16 + (lane & 15)) * 40 + (lane >> 4) * 8]);
        #pragma unroll
        for (int n = 0; n < 4; n++)
            b[n] = *reinterpret_cast<const f16x8*>(&Bl[(wc * 64 + n * 16 + (lane & 15)) * 40 + (lane >> 4) * 8]);
        #pragma unroll
        for (int m = 0; m < 4; m++)
            #pragma unroll
            for (int n = 0; n < 4; n++)
                acc[m][n] = __builtin_amdgcn_mfma_f32_16x16x32_f16(a[m], b[n], acc[m][n], 0, 0, 0);
    }

    const int rowb = m0 + wr * 64, colb = n0 + wc * 64;
    #pragma unroll
    for (int n = 0; n < 4; n++) {
        int cN = colb + n * 16 + (lane & 15);
        float bvv = bias[cN];
        int h = cN >> 6, d = cN & 63;
        #pragma unroll
        for (int m = 0; m < 4; m++) {
            #pragma unroll
            for (int rg = 0; rg < 4; rg++) {
                int r = rowb + m * 16 + (lane >> 4) * 4 + rg;
                int s = r >> 1, bi = r & 1;                 // row = s*B + b, B=2
                float val = acc[m][n][rg] + bvv;
                if (mode < 2) {
                    float pv = __shfl_xor(val, 1);          // partner col cN^1 == lane^1
                    if (d < 32) {
                        int fi = d >> 1;
                        float cc = rc[s * 16 + fi], ss = rs[s * 16 + fi];
                        val = ((d & 1) == 0) ? val * cc - pv * ss : val * cc + pv * ss;
                    }
                    if (mode == 0) val *= 0.18033688f;      // (1/8)*log2(e): base-2 softmax domain
                    ((mode == 0) ? qo : ko)[(((size_t)bi * NHEADS + h) * S_LEN + s) * HD + d] = (f16)val;
                } else {
                    vo[(((size_t)bi * NHEADS + h) * HD + d) * S_LEN + s] = (f16)val;
                }
            }
        }
    }
}

// ---------------- flash attention (swapped-operand MFMA) ----------------
// grid (S/64, B*H); 4 waves x 16 q-rows each.
// QK: mfma(K,Q) -> score col = q = lane&15 (lane-local softmax rows)
// PV: mfma(V^T,P) -> ctx col = q = lane&15 (lane-local rescale & epilogue)
__global__ __launch_bounds__(256) void attn_fwd(
    const f16* __restrict__ qb, const f16* __restrict__ kb,
    const f16* __restrict__ vt, f16* __restrict__ ctx)
{
    __shared__ f16 Kl[64 * 72];
    __shared__ f16 Vl[64 * 72];
    __shared__ f16 Pl[4 * 16 * 72];

    const int t = threadIdx.x, lane = t & 63, wid = t >> 6;
    const int q15 = lane & 15, g = lane >> 4;
    const int bh = blockIdx.y;
    const int q0 = blockIdx.x * 64 + wid * 16;

    // Q B-frag: lane holds Q[q15][g*8..+7] and +32
    const f16* qptr = qb + ((size_t)bh * S_LEN + q0) * HD;
    f16x8 qf0 = *reinterpret_cast<const f16x8*>(&qptr[q15 * HD + g * 8]);
    f16x8 qf1 = *reinterpret_cast<const f16x8*>(&qptr[q15 * HD + g * 8 + 32]);

    f32x4 ctxa[4];                          // [n][rg]: row d=16n+4g+rg, col q=q15
    #pragma unroll
    for (int i = 0; i < 4; i++) ctxa[i] = f32x4{0.f, 0.f, 0.f, 0.f};
    float mrun = -3.0e38f, lrun = 0.f;

    // staging map: 256 threads cover a 64x64 f16 tile with TWO 16B stores each
    const int r_st = t >> 2, c_st = (t & 3) * 16;
    const f16* kg = kb + (size_t)bh * S_LEN * HD + (size_t)r_st * HD + c_st;
    const f16* vg = vt + (size_t)bh * HD * S_LEN + (size_t)r_st * S_LEN + c_st;
    f16* kl_st = &Kl[r_st * 72 + c_st];
    f16* vl_st = &Vl[r_st * 72 + c_st];
    f16* pbase = &Pl[wid * 1152];

    for (int kt = 0; kt < S_LEN / 64; kt++) {
        __syncthreads();                    // prior-iter PV reads of Vl done
        *reinterpret_cast<uint4*>(kl_st)     = *reinterpret_cast<const uint4*>(kg);
        *reinterpret_cast<uint4*>(kl_st + 8) = *reinterpret_cast<const uint4*>(kg + 8);
        *reinterpret_cast<uint4*>(vl_st)     = *reinterpret_cast<const uint4*>(vg);
        *reinterpret_cast<uint4*>(vl_st + 8) = *reinterpret_cast<const uint4*>(vg + 8);
        kg += 64 * HD;
        vg += 64;
        __syncthreads();

        // QK^T swapped: sc[f][rg] = score(k = kt*64+16f+4g+rg, q = q0+q15)
        f32x4 sc[4];
        #pragma unroll
        for (int f = 0; f < 4; f++) {
            f16x8 kf0 = *reinterpret_cast<const f16x8*>(&Kl[(f * 16 + q15) * 72 + g * 8]);
            f16x8 kf1 = *reinterpret_cast<const f16x8*>(&Kl[(f * 16 + q15) * 72 + g * 8 + 32]);
            f32x4 z = {0.f, 0.f, 0.f, 0.f};
            z = __builtin_amdgcn_mfma_f32_16x16x32_f16(kf0, qf0, z, 0, 0, 0);
            sc[f] = __builtin_amdgcn_mfma_f32_16x16x32_f16(kf1, qf1, z, 0, 0, 0);
        }

        // online softmax (base-2); all stats lane-local for q = q15
        float pmf[4];
        #pragma unroll
        for (int f = 0; f < 4; f++)
            pmf[f] = fmaxf(fmaxf(sc[f][0], sc[f][1]), fmaxf(sc[f][2], sc[f][3]));
        float pmax = fmaxf(fmaxf(pmf[0], pmf[1]), fmaxf(pmf[2], pmf[3]));
        pmax = fmaxf(pmax, __shfl_xor(pmax, 16));
        pmax = fmaxf(pmax, __shfl_xor(pmax, 32));
        float mnew = fmaxf(mrun, pmax);
        float scale = __builtin_amdgcn_exp2f(mrun - mnew);
        float tsum = 0.f;
        #pragma unroll
        for (int f = 0; f < 4; f++)
            #pragma unroll
            for (int rg = 0; rg < 4; rg++) {
                float p = __builtin_amdgcn_exp2f(sc[f][rg] - mnew);
                sc[f][rg] = p;
                tsum += p;
            }
        tsum += __shfl_xor(tsum, 16);
        tsum += __shfl_xor(tsum, 32);
        lrun = lrun * scale + tsum;
        mrun = mnew;
        #pragma unroll
        for (int n = 0; n < 4; n++) {
            ctxa[n][0] *= scale; ctxa[n][1] *= scale;
            ctxa[n][2] *= scale; ctxa[n][3] *= scale;
        }

        // P -> per-wave LDS: lane q15 owns row q, writes 4 contiguous k per f (b64)
        #pragma unroll
        for (int f = 0; f < 4; f++) {
            f16x4 pw = { (f16)sc[f][0], (f16)sc[f][1], (f16)sc[f][2], (f16)sc[f][3] };
            *reinterpret_cast<f16x4*>(&pbase[q15 * 72 + f * 16 + g * 4]) = pw;
        }
        // same-wave visibility: drain LDS writes, pin ordering (no block barrier needed)
        asm volatile("s_waitcnt lgkmcnt(0)" ::: "memory");
        __builtin_amdgcn_sched_barrier(0);

        // PV swapped: ctx[d][q] += V^T[d][s] * P[q][s]
        #pragma unroll
        for (int c = 0; c < 2; c++) {
            f16x8 pf = *reinterpret_cast<const f16x8*>(&pbase[q15 * 72 + g * 8 + c * 32]);
            #pragma unroll
            for (int n = 0; n < 4; n++) {
                f16x8 vf = *reinterpret_cast<const f16x8*>(&Vl[(n * 16 + q15) * 72 + g * 8 + c * 32]);
                ctxa[n] = __builtin_amdgcn_mfma_f32_16x16x32_f16(vf, pf, ctxa[n], 0, 0, 0);
            }
        }
    }

    // epilogue: lane-local 1/l, packed b64 stores (d = 16n+4g+rg contiguous in rg)
    const int bi = bh >> 4, h = bh & 15;
    const int s = q0 + q15;
    float inv = 1.0f / lrun;
    f16* outp = &ctx[((size_t)s * BATCH + bi) * DMODEL + h * HD];
    #pragma unroll
    for (int n = 0; n < 4; n++) {
        f16x4 o = { (f16)(ctxa[n][0] * inv), (f16)(ctxa[n][1] * inv),
                    (f16)(ctxa[n][2] * inv), (f16)(ctxa[n][3] * inv) };
        *reinterpret_cast<f16x4*>(&outp[n * 16 + g * 4]) = o;
    }
}

// ---------------- output projection: f16 X (ws), fp32 W (global), fp32 out ----------------
__global__ __launch_bounds__(256) void out_gemm(
    const f16* __restrict__ X, const float* __restrict__ W,
    const float* __restrict__ bias, float* __restrict__ out)
{
    __shared__ f16 Al[128 * 40];
    __shared__ f16 Bl[128 * 40];

    const int t = threadIdx.x;
    const int lane = t & 63, wid = t >> 6;
    const int wr = wid >> 1, wc = wid & 1;
    const int m0 = blockIdx.x * 128, n0 = blockIdx.y * 128;

    f32x4 acc[4][4];
    #pragma unroll
    for (int m = 0; m < 4; m++)
        #pragma unroll
        for (int n = 0; n < 4; n++)
            acc[m][n] = f32x4{0.f, 0.f, 0.f, 0.f};

    for (int k0 = 0; k0 < DMODEL; k0 += 32) {
        __syncthreads();
        #pragma unroll
        for (int i = 0; i < 2; i++) {
            int e = (i * 256 + t) * 8;
            int r = e >> 5, c = e & 31;
            *reinterpret_cast<uint4*>(&Al[r * 40 + c]) =
                *reinterpret_cast<const uint4*>(&X[(size_t)(m0 + r) * DMODEL + k0 + c]);
            {
                const float* src = &W[(size_t)(n0 + r) * DMODEL + k0 + c];
                float4 v0 = *reinterpret_cast<const float4*>(src);
                float4 v1 = *reinterpret_cast<const float4*>(src + 4);
                f16x8 h = { (f16)v0.x, (f16)v0.y, (f16)v0.z, (f16)v0.w,
                            (f16)v1.x, (f16)v1.y, (f16)v1.z, (f16)v1.w };
                *reinterpret_cast<f16x8*>(&Bl[r * 40 + c]) = h;
            }
        }
        __syncthreads();
        f16x8 a[4], b[4];
        #pragma unroll
        for (int m = 0; m < 4; m++)
            a[m] = *reinterpret_cast<const f16x8*>(&Al[(wr * 64 + m * 16 + (lane & 15)) * 40 + (lane >> 4) * 8]);
        #pragma unroll
        for (int n = 0; n < 4; n++)
            b[n] = *reinterpret_cast<const f16x8*>(&Bl[(wc * 64 + n * 16 + (lane & 15)) * 40 + (lane >> 4) * 8]);
        #pragma unroll
        for (int m = 0; m < 4; m++)
            #pragma unroll
            for (int n = 0; n < 4; n++)
                acc[m][n] = __builtin_amdgcn_mfma_f32_16x16x32_f16(a[m], b[n], acc[m][n], 0, 0, 0);
    }

    const int rowb = m0 + wr * 64, colb = n0 + wc * 64;
    #pragma unroll
    for (int n = 0; n < 4; n++) {
        int cN = colb + n * 16 + (lane & 15);
        float bvv = bias[cN];
        #pragma unroll
        for (int m = 0; m < 4; m++) {
            #pragma unroll
            for (int rg = 0; rg < 4; rg++) {
                int r = rowb + m * 16 + (lane >> 4) * 4 + rg;
                out[(size_t)r * DMODEL + cN] = acc[m][n][rg] + bvv;
            }
        }
    }
}

// ---------------- launch ----------------
extern "C" void kernel_launch(void* const* d_in, const int* in_sizes, int n_in,
                              void* d_out, int out_size, void* d_ws, size_t ws_size,
                              hipStream_t stream)
{
    const float* Q  = (const float*)d_in[0];
    const float* K  = (const float*)d_in[1];
    const float* V  = (const float*)d_in[2];
    const float* Wq = (const float*)d_in[3];
    const float* bq = (const float*)d_in[4];
    const float* Wk = (const float*)d_in[5];
    const float* bk = (const float*)d_in[6];
    const float* Wv = (const float*)d_in[7];
    const float* bv = (const float*)d_in[8];
    const float* Wo = (const float*)d_in[9];
    const float* bo = (const float*)d_in[10];
    float* out = (float*)d_out;

    // workspace layout (total 32.25 MiB):
    //   [0,128K)    rc    [128K,256K) rs
    //   [256K, +8M) qbuf  (B,H,S,hd) f16
    //   [+8M,+16M)  kbuf  (B,H,S,hd) f16
    //   [+16M,+24M) vtb   (B,H,hd,S) f16
    //   [+24M,+32M) ctxb  (S*B, D)   f16
    char* w = (char*)d_ws;
    const size_t szT = (size_t)S_LEN * 16 * sizeof(float);     // 128 KiB
    const size_t szQ = (size_t)MROWS * DMODEL * sizeof(f16);   // 8 MiB
    float* rc  = (float*)(w);
    float* rs  = (float*)(w + szT);
    f16* qbuf = (f16*)(w + 2 * szT);
    f16* kbuf = (f16*)(w + 2 * szT + szQ);
    f16* vtb  = (f16*)(w + 2 * szT + 2 * szQ);
    f16* ctxb = (f16*)(w + 2 * szT + 3 * szQ);

    rope_table<<<(S_LEN * 16) / 256, 256, 0, stream>>>(rc, rs);

    proj_gemm<<<dim3(MROWS / 128, DMODEL / 128, 3), 256, 0, stream>>>(
        Q, K, V, Wq, Wk, Wv, bq, bk, bv, qbuf, kbuf, vtb, rc, rs);

    attn_fwd<<<dim3(S_LEN / 64, BATCH * NHEADS), 256, 0, stream>>>(qbuf, kbuf, vtb, ctxb);

    out_gemm<<<dim3(MROWS / 128, DMODEL / 128), 256, 0, stream>>>(ctxb, Wo, bo, out);
}